// Round 7
// baseline (1563.145 us; speedup 1.0000x reference)
//
#include <hip/hip_runtime.h>
#include <hip/hip_bf16.h>
#include <math.h>

#define B_ 4
#define S_ 4096
#define D_ 2048
#define DC_ 512
#define DFF_ 8192

typedef __attribute__((ext_vector_type(8))) __bf16 bf16x8;
typedef __attribute__((ext_vector_type(4))) float f32x4;

__device__ __forceinline__ float gelu_exact(float x) {
    return 0.5f * x * (1.0f + erff(x * 0.70710678118654752f));
}

__device__ __forceinline__ unsigned short f2bf_bits(float f) {
    __hip_bfloat16 h = __float2bfloat16(f);
    return *reinterpret_cast<unsigned short*>(&h);
}

#define GLD16(gptr, lptr) \
    __builtin_amdgcn_global_load_lds( \
        (__attribute__((address_space(1))) void*)(gptr), \
        (__attribute__((address_space(3))) void*)(lptr), 16, 0, 0)

// ---------------- pooled mean (deterministic 2-stage) ----------------
__global__ void pool_partial_k(const float* __restrict__ hidden, float* __restrict__ pp) {
    int d = blockIdx.x * 256 + threadIdx.x;
    int sc = blockIdx.y;
    int b = blockIdx.z;
    const float* base = hidden + ((size_t)b * S_ + (size_t)sc * 512) * D_ + d;
    float s = 0.f;
    #pragma unroll 4
    for (int i = 0; i < 512; ++i) s += base[(size_t)i * D_];
    pp[((size_t)sc * B_ + b) * D_ + d] = s;
}

__global__ void pool_reduce_k(const float* __restrict__ pp, float* __restrict__ pooled) {
    int tid = blockIdx.x * 256 + threadIdx.x;   // B_*D_ threads
    int b = tid >> 11;
    int d = tid & (D_ - 1);
    float s = 0.f;
    for (int sc = 0; sc < 8; ++sc) s += pp[((size_t)sc * B_ + b) * D_ + d];
    pooled[tid] = s * (1.0f / (float)S_);
}

// ---------------- router logits (fp32, one wave per token) ----------------
__global__ __launch_bounds__(256) void logits_k(const float* __restrict__ hidden,
                                                const float* __restrict__ rw,
                                                const float* __restrict__ rb,
                                                float* __restrict__ logits) {
    int tok = blockIdx.x * 4 + (threadIdx.x >> 6);
    int lane = threadIdx.x & 63;
    const float4* row = (const float4*)(hidden + (size_t)tok * D_);
    const float4* w4 = (const float4*)rw;
    float s = 0.f;
    #pragma unroll
    for (int i = 0; i < 8; ++i) {
        float4 v = row[i * 64 + lane];
        float4 w = w4[i * 64 + lane];
        s += (v.x * w.x + v.y * w.y) + (v.z * w.z + v.w * w.w);
    }
    #pragma unroll
    for (int off = 32; off > 0; off >>= 1) s += __shfl_down(s, off, 64);
    if (lane == 0) logits[tok] = s + rb[0];
}

// ---------------- complexity head ----------------
__global__ __launch_bounds__(256) void head1_k(const float* __restrict__ pooled,
                                               const float* __restrict__ w1,
                                               const float* __restrict__ b1,
                                               float* __restrict__ ch) {
    __shared__ float red[256];
    int b = blockIdx.y;
    int cl = threadIdx.x & 63;
    int c = blockIdx.x * 64 + cl;
    int ks = threadIdx.x >> 6;                 // 0..3 K-slice
    const float* pr = pooled + b * D_ + ks * 512;
    const float* wp = w1 + (size_t)(ks * 512) * DC_ + c;
    float acc = 0.f;
    #pragma unroll 8
    for (int i = 0; i < 512; ++i) acc += pr[i] * wp[(size_t)i * DC_];
    red[threadIdx.x] = acc;
    __syncthreads();
    if (ks == 0) {
        float s = ((red[cl] + red[cl + 64]) + (red[cl + 128] + red[cl + 192]));
        ch[b * DC_ + c] = gelu_exact(s + b1[c]);
    }
}

__global__ void head2_k(const float* __restrict__ ch, const float* __restrict__ w2,
                        const float* __restrict__ b2, int* __restrict__ kbuf) {
    __shared__ float red[4];
    int t = threadIdx.x;
    int b = t >> 6, lane = t & 63;
    float acc = 0.f;
    #pragma unroll
    for (int i = 0; i < 8; ++i) acc += ch[b * DC_ + i * 64 + lane] * w2[i * 64 + lane];
    #pragma unroll
    for (int off = 32; off > 0; off >>= 1) acc += __shfl_down(acc, off, 64);
    if (lane == 0) {
        float z = acc + b2[0];
        float cx = 1.f / (1.f + expf(-z));
        red[b] = 0.25f + cx * 0.75f;
    }
    __syncthreads();
    if (t == 0) {
        float cap = ((red[0] + red[1]) + (red[2] + red[3])) * 0.25f;
        int kk = (int)((double)cap * (double)S_);
        if (kk < 0) kk = 0;
        if (kk > S_) kk = S_;
        kbuf[0] = kk;
    }
}

// ---------------- per-batch top-k select (radix select + compaction) ----------------
__global__ __launch_bounds__(256) void select_k(const float* __restrict__ logits,
                                                const int* __restrict__ kbuf,
                                                int* __restrict__ gidx,
                                                float* __restrict__ gwt) {
    int b = blockIdx.x;
    int t = threadIdx.x;
    int k = kbuf[0];
    __shared__ float slog[S_];
    __shared__ unsigned su[S_];
    __shared__ int hist[256];
    __shared__ unsigned sprefix;
    __shared__ int srem;
    __shared__ int sg[256], se[256];

    for (int i = t; i < S_; i += 256) {
        float f = logits[b * S_ + i];
        slog[i] = f;
        unsigned ub = __float_as_uint(f);
        su[i] = (ub & 0x80000000u) ? ~ub : (ub | 0x80000000u);
    }
    if (t == 0) { sprefix = 0u; srem = k; }
    __syncthreads();

    for (int round = 0; round < 4; ++round) {
        int shift = 24 - round * 8;
        hist[t] = 0;
        __syncthreads();
        unsigned pref = sprefix;
        unsigned pmask = (round == 0) ? 0u : ~((1u << (shift + 8)) - 1u);
        for (int i = t; i < S_; i += 256) {
            unsigned u = su[i];
            if ((u & pmask) == (pref & pmask))
                atomicAdd(&hist[(u >> shift) & 255], 1);
        }
        __syncthreads();
        if (t == 0) {
            int rem = srem, run = 0;
            for (int v = 255; v >= 0; --v) {
                int h = hist[v];
                if (run + h >= rem) {
                    srem = rem - run;
                    sprefix = pref | ((unsigned)v << shift);
                    break;
                }
                run += h;
            }
        }
        __syncthreads();
    }
    unsigned T = sprefix;
    int need_eq = srem;

    int base = t * 16;
    int local_gt = 0, local_eq = 0;
    #pragma unroll
    for (int i = 0; i < 16; ++i) {
        unsigned u = su[base + i];
        local_gt += (u > T);
        local_eq += (u == T);
    }
    sg[t] = local_gt; se[t] = local_eq;
    __syncthreads();
    for (int o = 1; o < 256; o <<= 1) {
        int vg = (t >= o) ? sg[t - o] : 0;
        int ve = (t >= o) ? se[t - o] : 0;
        __syncthreads();
        sg[t] += vg; se[t] += ve;
        __syncthreads();
    }
    int gt_excl = sg[t] - local_gt;
    int eq_excl = se[t] - local_eq;
    int total_gt = sg[255];

    int gpos = gt_excl, epos = eq_excl;
    for (int i = 0; i < 16; ++i) {
        int s = base + i;
        unsigned u = su[s];
        int pos = -1;
        if (u > T) pos = gpos++;
        else if (u == T) { if (epos < need_eq) pos = total_gt + epos; epos++; }
        if (pos >= 0) {
            gidx[b * k + pos] = b * S_ + s;
            gwt[b * k + pos] = 1.f / (1.f + expf(-slog[s]));
        }
    }
}

// ---------------- gather selected rows -> packed bf16 A ----------------
__global__ void gather_k(const float* __restrict__ hidden, const int* __restrict__ gidx,
                         const int* __restrict__ kbuf, __hip_bfloat16* __restrict__ Ag) {
    int tid = blockIdx.x * 256 + threadIdx.x;  // B_*S_*(D_/4) worst case
    int m = tid >> 9, c4 = tid & 511;
    int M = B_ * kbuf[0];
    if (m >= M) return;
    int row = gidx[m];
    float4 v = ((const float4*)(hidden + (size_t)row * D_))[c4];
    ushort4 o;
    o.x = f2bf_bits(v.x); o.y = f2bf_bits(v.y); o.z = f2bf_bits(v.z); o.w = f2bf_bits(v.w);
    ((ushort4*)Ag)[tid] = o;
}

// ---------------- fp32 -> bf16 transpose (for B^T GEMM layout) ----------------
__global__ void transpose_cvt_k(const float* __restrict__ in, __hip_bfloat16* __restrict__ out,
                                int R, int C) {
    __shared__ float tile[32][33];
    int r0 = blockIdx.y * 32, c0 = blockIdx.x * 32;
    int tx = threadIdx.x, ty = threadIdx.y;
    #pragma unroll
    for (int i = 0; i < 32; i += 8)
        tile[ty + i][tx] = in[(size_t)(r0 + ty + i) * C + (c0 + tx)];
    __syncthreads();
    #pragma unroll
    for (int i = 0; i < 32; i += 8)
        out[(size_t)(c0 + ty + i) * R + (r0 + tx)] = __float2bfloat16(tile[tx][ty + i]);
}

// Chunk-major transpose for w2: in [R=DFF_][C=D_] -> out [R/CH][C][CH].
// Makes gemm2's B-panel (256 n-rows x CH k-cols) a CONTIGUOUS 2 MB region
// (row stride CH, matching gemm1's stride-class) instead of 16 KB-strided
// slices of a [C][DFF_] buffer.
__global__ void transpose_cvt_chunk_k(const float* __restrict__ in,
                                      __hip_bfloat16* __restrict__ out,
                                      int R, int C, int CH, int chsh) {
    __shared__ float tile[32][33];
    int r0 = blockIdx.y * 32, c0 = blockIdx.x * 32;
    int tx = threadIdx.x, ty = threadIdx.y;
    #pragma unroll
    for (int i = 0; i < 32; i += 8)
        tile[ty + i][tx] = in[(size_t)(r0 + ty + i) * C + (c0 + tx)];
    __syncthreads();
    size_t cbase = (size_t)(r0 >> chsh) * ((size_t)C * CH) + (r0 & (CH - 1)) + tx;
    #pragma unroll
    for (int i = 0; i < 32; i += 8)
        out[cbase + (size_t)(c0 + ty + i) * CH] = __float2bfloat16(tile[tx][ty + i]);
}

// =====================================================================
// 256x256 BK=64, 8-wave, 8-phase double-buffered MFMA GEMM (gload_lds).
// R6 post-mortem: the SWZ=1 chunked swizzle assigned all M-clipped dead
// blocks (logical 320..511) to XCDs 5-7 -> 3 XCDs idle (Occupancy 12.6%).
// Fix: compute the m204 bijective chunk swizzle over the ACTIVE block
// count (kbuf-derived), and order logical ids n-panel-major so each XCD
// owns ONE 2MB B-panel (L2-resident) and sweeps M (A streams via L3).
// =====================================================================

#define FENCE_() asm volatile("" ::: "memory")
#define BARR_()  do { FENCE_(); __builtin_amdgcn_s_barrier(); FENCE_(); } while (0)
#define VMW_()   do { asm volatile("s_waitcnt vmcnt(6)" ::: "memory"); \
                      __builtin_amdgcn_sched_barrier(0); } while (0)

template <int BN, int EPI, int SWZ>
__global__ __launch_bounds__(512, 2) void gemm8p(
    const __hip_bfloat16* __restrict__ A, int lda,
    const __hip_bfloat16* __restrict__ BT, int ldb,
    const float* __restrict__ bias,
    __hip_bfloat16* __restrict__ Hout, int ldh,
    float* __restrict__ out,
    const int* __restrict__ gidx, const float* __restrict__ gwt,
    const int* __restrict__ kbuf, int K, int first)
{
    constexpr int NQ = BN / 128;          // B frags per quadrant per wave
    constexpr int NF = 2 * NQ;            // total N frags per wave
    constexpr int BUFB = BN * 128;        // bytes per B LDS buffer
    extern __shared__ char lds[];         // A: [0,64K)  B: [64K, 64K+2*BUFB)

    const int M = B_ * kbuf[0];
    int bx, by;
    if constexpr (SWZ) {
        // active-aware m204 bijective XCD-chunk swizzle, n-panel-major:
        // XCD x gets a contiguous logical chunk; logical id decomposes as
        // bx = lg / mb (n-panel, ~constant per XCD -> B-panel L2-pinned),
        // by = lg % mb (M-sweep).
        const int mb = (M + 255) >> 8;
        const int nact = mb * gridDim.x;
        const int flat = blockIdx.y * gridDim.x + blockIdx.x;
        if (flat >= nact) return;          // dead blocks: round-robin, exit fast
        const int q = nact >> 3, r = nact & 7;
        const int x = flat & 7, idx = flat >> 3;
        const int lg = (x < r) ? x * (q + 1) + idx
                               : r * (q + 1) + (x - r) * q + idx;
        by = lg % mb;
        bx = lg / mb;
    } else {
        bx = blockIdx.x; by = blockIdx.y;
    }
    const int m0 = by * 256;
    if (m0 >= M) return;
    const int n0 = bx * BN;

    const int t = threadIdx.x;
    const int lane = t & 63;
    const int wave = t >> 6;
    const int wr = wave >> 2, wc = wave & 3;   // 2 x 4 wave grid

    // staging constants: thread t covers 16B of local row rl; the source
    // column is XOR-swizzled so a linear LDS write yields swizzled content.
    const int rl = t >> 3;
    const int cbs = ((t & 7) << 4) ^ ((rl & 7) << 4);
    const int wchunk = (t >> 6) << 10;         // wave-uniform LDS chunk

    bf16x8 aR[4][2], bR[NQ][2];
    f32x4 acc[8][NF] = {};

    auto STG = [&](const __hip_bfloat16* src, int row0, int rowMax, int kcol,
                   int ld, int ldsoff) {
        int gr = row0 + rl;
        if (gr > rowMax) gr = rowMax;
        GLD16(src + (size_t)gr * ld + (kcol + (cbs >> 1)), lds + ldsoff + wchunk);
    };
    auto SA = [&](int buf, int h, int kt) {      // stage A half h (128 rows)
        int bo = buf * 32768 + h * 16384;
        STG(A, m0 + h * 128,      M - 1, kt * 64, lda, bo);
        STG(A, m0 + h * 128 + 64, M - 1, kt * 64, lda, bo + 8192);
    };
    auto SB = [&](int buf, int v, int kt) {      // stage B half v (BN/2 rows)
        int bo = 65536 + buf * BUFB + v * (BUFB / 2);
        if constexpr (BN == 256) {
            STG(BT, n0 + v * 128,      0x7fffffff, kt * 64, ldb, bo);
            STG(BT, n0 + v * 128 + 64, 0x7fffffff, kt * 64, ldb, bo + 8192);
        } else {
            STG(BT, n0 + v * 64, 0x7fffffff, kt * 64, ldb, bo);
        }
    };
    auto RA = [&](int buf, int h) {
        int bo = buf * 32768;
        #pragma unroll
        for (int q2 = 0; q2 < 4; ++q2) {
            int row = h * 128 + wr * 64 + q2 * 16 + (lane & 15);
            int ro = bo + row * 128;
            int sw = (row & 7) << 4;
            #pragma unroll
            for (int ks = 0; ks < 2; ++ks)
                aR[q2][ks] = *(const bf16x8*)(lds + ro + ((ks * 64 + ((lane >> 4) << 4)) ^ sw));
        }
    };
    auto RB = [&](int buf, int v) {
        int bo = 65536 + buf * BUFB;
        #pragma unroll
        for (int q2 = 0; q2 < NQ; ++q2) {
            int row = v * (BN / 2) + wc * (BN / 8) + q2 * 16 + (lane & 15);
            int ro = bo + row * 128;
            int sw = (row & 7) << 4;
            #pragma unroll
            for (int ks = 0; ks < 2; ++ks)
                bR[q2][ks] = *(const bf16x8*)(lds + ro + ((ks * 64 + ((lane >> 4) << 4)) ^ sw));
        }
    };
    auto MM = [&](int h, int v) {
        __builtin_amdgcn_s_setprio(1);
        #pragma unroll
        for (int mi = 0; mi < 4; ++mi)
            #pragma unroll
            for (int nj = 0; nj < NQ; ++nj)
                #pragma unroll
                for (int ks = 0; ks < 2; ++ks)
                    acc[h * 4 + mi][v * NQ + nj] = __builtin_amdgcn_mfma_f32_16x16x32_bf16(
                        aR[mi][ks], bR[nj][ks], acc[h * 4 + mi][v * NQ + nj], 0, 0, 0);
        __builtin_amdgcn_s_setprio(0);
    };

    const int nkt = K >> 6;
    const int nit = K >> 7;

    // prologue: K-tile0 fully + K-tile1 {A0,B1,A1}; tile1.B0 staged at ph1.
    SA(0, 0, 0); SA(0, 1, 0); SB(0, 0, 0); SB(0, 1, 0);
    SA(1, 0, 1); SB(1, 1, 1); SA(1, 1, 1);
    VMW_(); BARR_();

    for (int it = 0; it < nit; ++it) {
        int k1 = 2 * it + 1;
        int k2 = 2 * it + 2; if (k2 > nkt - 1) k2 = nkt - 1;
        int k3 = 2 * it + 3; if (k3 > nkt - 1) k3 = nkt - 1;
        // ph1..ph4: K-tile 2it from buf0
        RA(0, 0); RB(0, 0); SB(1, 0, k1); BARR_(); MM(0, 0); BARR_();
        RB(0, 1);           SA(0, 0, k2); BARR_(); MM(0, 1); BARR_();
        RA(0, 1);           SB(0, 1, k2); BARR_(); MM(1, 1); BARR_();
        RB(0, 0);           SA(0, 1, k2); BARR_(); MM(1, 0); VMW_(); BARR_();
        // ph5..ph8: K-tile 2it+1 from buf1
        RA(1, 0); RB(1, 0); SB(0, 0, k2); BARR_(); MM(0, 0); BARR_();
        RB(1, 1);           SA(1, 0, k3); BARR_(); MM(0, 1); BARR_();
        RA(1, 1);           SB(1, 1, k3); BARR_(); MM(1, 1); BARR_();
        RB(1, 0);           SA(1, 1, k3); BARR_(); MM(1, 0); VMW_(); BARR_();
    }
    asm volatile("s_waitcnt vmcnt(0)" ::: "memory");

    // epilogue
    const int qrow = (lane >> 4) << 2, qcol = lane & 15;
    #pragma unroll
    for (int f = 0; f < 8; ++f) {
        const int h = f >> 2, mi = f & 3;
        const int mbase = m0 + h * 128 + wr * 64 + mi * 16 + qrow;
        if constexpr (EPI == 0) {
            #pragma unroll
            for (int g = 0; g < NF; ++g) {
                const int v = g / NQ, nj = g % NQ;
                const int col = n0 + v * (BN / 2) + wc * (BN / 8) + nj * 16 + qcol;
                const float bv = bias[col];
                #pragma unroll
                for (int r = 0; r < 4; ++r) {
                    int m = mbase + r;
                    if (m < M)
                        Hout[(size_t)m * ldh + col] =
                            __float2bfloat16(gelu_exact(acc[f][g][r] + bv));
                }
            }
        } else {
            #pragma unroll
            for (int r = 0; r < 4; ++r) {
                int m = mbase + r;
                if (m < M) {
                    int grow = gidx[m];
                    float wgt = gwt[m];
                    float* orow = out + (size_t)grow * D_;
                    #pragma unroll
                    for (int g = 0; g < NF; ++g) {
                        const int v = g / NQ, nj = g % NQ;
                        const int col = n0 + v * (BN / 2) + wc * (BN / 8) + nj * 16 + qcol;
                        float vv = acc[f][g][r];
                        if (first) vv += bias[col];
                        orow[col] += wgt * vv;
                    }
                }
            }
        }
    }
}

extern "C" void kernel_launch(void* const* d_in, const int* in_sizes, int n_in,
                              void* d_out, int out_size, void* d_ws, size_t ws_size,
                              hipStream_t stream) {
    (void)in_sizes; (void)n_in;
    const float* hidden = (const float*)d_in[0];
    const float* rw  = (const float*)d_in[1];
    const float* rb  = (const float*)d_in[2];
    const float* cw1 = (const float*)d_in[3];
    const float* cb1 = (const float*)d_in[4];
    const float* cw2 = (const float*)d_in[5];
    const float* cb2 = (const float*)d_in[6];
    const float* fw1 = (const float*)d_in[7];
    const float* fb1 = (const float*)d_in[8];
    const float* fw2 = (const float*)d_in[9];
    const float* fb2 = (const float*)d_in[10];

    char* ws = (char*)d_ws;
    size_t off = 0;
    auto alloc = [&](size_t bytes) {
        size_t r = (off + 255) & ~(size_t)255;
        off = r + bytes;
        return r;
    };
    size_t o_logits = alloc((size_t)B_ * S_ * 4);
    size_t o_pp     = alloc((size_t)8 * B_ * D_ * 4);
    size_t o_pooled = alloc((size_t)B_ * D_ * 4);
    size_t o_ch     = alloc((size_t)B_ * DC_ * 4);
    size_t o_k      = alloc(256);
    size_t o_gidx   = alloc((size_t)B_ * S_ * 4);
    size_t o_gwt    = alloc((size_t)B_ * S_ * 4);
    size_t o_w1T    = alloc((size_t)D_ * DFF_ * 2);
    size_t o_w2T    = alloc((size_t)D_ * DFF_ * 2);
    size_t o_Ag     = alloc((size_t)B_ * S_ * D_ * 2);
    size_t base     = (off + 255) & ~(size_t)255;
    int CH = DFF_;
    while (CH > 256 && base + (size_t)B_ * S_ * CH * 2 > ws_size) CH >>= 1;
    size_t o_H = alloc((size_t)B_ * S_ * CH * 2);
    int chsh = 31 - __builtin_clz((unsigned)CH);

    float* logits = (float*)(ws + o_logits);
    float* pp     = (float*)(ws + o_pp);
    float* pooled = (float*)(ws + o_pooled);
    float* ch     = (float*)(ws + o_ch);
    int*   kbuf   = (int*)(ws + o_k);
    int*   gidx   = (int*)(ws + o_gidx);
    float* gwt    = (float*)(ws + o_gwt);
    __hip_bfloat16* w1T = (__hip_bfloat16*)(ws + o_w1T);
    __hip_bfloat16* w2T = (__hip_bfloat16*)(ws + o_w2T);
    __hip_bfloat16* Ag  = (__hip_bfloat16*)(ws + o_Ag);
    __hip_bfloat16* H   = (__hip_bfloat16*)(ws + o_H);
    float* out = (float*)d_out;

    // allow >64KB dynamic LDS for the 8-phase GEMMs (idempotent, ~us)
    hipError_t e;
    e = hipFuncSetAttribute((const void*)gemm8p<256, 0, 0>,
                            hipFuncAttributeMaxDynamicSharedMemorySize, 131072);
    e = hipFuncSetAttribute((const void*)gemm8p<256, 1, 1>,
                            hipFuncAttributeMaxDynamicSharedMemorySize, 131072);
    (void)e;

    pool_partial_k<<<dim3(D_ / 256, 8, B_), 256, 0, stream>>>(hidden, pp);
    pool_reduce_k<<<dim3(B_ * D_ / 256), 256, 0, stream>>>(pp, pooled);
    logits_k<<<dim3(B_ * S_ / 4), 256, 0, stream>>>(hidden, rw, rb, logits);
    head1_k<<<dim3(DC_ / 64, B_), 256, 0, stream>>>(pooled, cw1, cb1, ch);
    head2_k<<<dim3(1), 256, 0, stream>>>(ch, cw2, cb2, kbuf);
    select_k<<<dim3(B_), 256, 0, stream>>>(logits, kbuf, gidx, gwt);
    gather_k<<<dim3(B_ * S_ * (D_ / 4) / 256), 256, 0, stream>>>(hidden, gidx, kbuf, Ag);
    transpose_cvt_k<<<dim3(DFF_ / 32, D_ / 32), dim3(32, 8), 0, stream>>>(fw1, w1T, D_, DFF_);
    // w2 -> chunk-major [DFF_/CH][D_][CH]
    transpose_cvt_chunk_k<<<dim3(D_ / 32, DFF_ / 32), dim3(32, 8), 0, stream>>>(
        fw2, w2T, DFF_, D_, CH, chsh);
    hipMemcpyAsync(d_out, (const void*)hidden, (size_t)out_size * 4,
                   hipMemcpyDeviceToDevice, stream);

    int nch = DFF_ / CH;
    for (int c = 0; c < nch; ++c) {
        gemm8p<256, 0, 0><<<dim3(CH / 256, B_ * S_ / 256), 512, 131072, stream>>>(
            Ag, D_, w1T + (size_t)c * CH * D_, D_, fb1 + c * CH,
            H, CH, nullptr, nullptr, nullptr, kbuf, D_, 0);
        gemm8p<256, 1, 1><<<dim3(D_ / 256, B_ * S_ / 256), 512, 131072, stream>>>(
            H, CH, w2T + (size_t)c * D_ * CH, CH, fb2,
            nullptr, 0, out, gidx, gwt, kbuf, CH, c == 0);
    }
}

// Round 8
// 1515.365 us; speedup vs baseline: 1.0315x; 1.0315x over previous
//
#include <hip/hip_runtime.h>
#include <hip/hip_bf16.h>
#include <math.h>

#define B_ 4
#define S_ 4096
#define D_ 2048
#define DC_ 512
#define DFF_ 8192

typedef __attribute__((ext_vector_type(8))) __bf16 bf16x8;
typedef __attribute__((ext_vector_type(4))) float f32x4;

__device__ __forceinline__ float gelu_exact(float x) {
    return 0.5f * x * (1.0f + erff(x * 0.70710678118654752f));
}

__device__ __forceinline__ unsigned short f2bf_bits(float f) {
    __hip_bfloat16 h = __float2bfloat16(f);
    return *reinterpret_cast<unsigned short*>(&h);
}

#define GLD16(gptr, lptr) \
    __builtin_amdgcn_global_load_lds( \
        (__attribute__((address_space(1))) void*)(gptr), \
        (__attribute__((address_space(3))) void*)(lptr), 16, 0, 0)

// ---------------- pooled mean (deterministic 2-stage) ----------------
__global__ void pool_partial_k(const float* __restrict__ hidden, float* __restrict__ pp) {
    int d = blockIdx.x * 256 + threadIdx.x;
    int sc = blockIdx.y;
    int b = blockIdx.z;
    const float* base = hidden + ((size_t)b * S_ + (size_t)sc * 512) * D_ + d;
    float s = 0.f;
    #pragma unroll 4
    for (int i = 0; i < 512; ++i) s += base[(size_t)i * D_];
    pp[((size_t)sc * B_ + b) * D_ + d] = s;
}

__global__ void pool_reduce_k(const float* __restrict__ pp, float* __restrict__ pooled) {
    int tid = blockIdx.x * 256 + threadIdx.x;   // B_*D_ threads
    int b = tid >> 11;
    int d = tid & (D_ - 1);
    float s = 0.f;
    for (int sc = 0; sc < 8; ++sc) s += pp[((size_t)sc * B_ + b) * D_ + d];
    pooled[tid] = s * (1.0f / (float)S_);
}

// ---------------- router logits (fp32, one wave per token) ----------------
__global__ __launch_bounds__(256) void logits_k(const float* __restrict__ hidden,
                                                const float* __restrict__ rw,
                                                const float* __restrict__ rb,
                                                float* __restrict__ logits) {
    int tok = blockIdx.x * 4 + (threadIdx.x >> 6);
    int lane = threadIdx.x & 63;
    const float4* row = (const float4*)(hidden + (size_t)tok * D_);
    const float4* w4 = (const float4*)rw;
    float s = 0.f;
    #pragma unroll
    for (int i = 0; i < 8; ++i) {
        float4 v = row[i * 64 + lane];
        float4 w = w4[i * 64 + lane];
        s += (v.x * w.x + v.y * w.y) + (v.z * w.z + v.w * w.w);
    }
    #pragma unroll
    for (int off = 32; off > 0; off >>= 1) s += __shfl_down(s, off, 64);
    if (lane == 0) logits[tok] = s + rb[0];
}

// ---------------- complexity head ----------------
__global__ __launch_bounds__(256) void head1_k(const float* __restrict__ pooled,
                                               const float* __restrict__ w1,
                                               const float* __restrict__ b1,
                                               float* __restrict__ ch) {
    __shared__ float red[256];
    int b = blockIdx.y;
    int cl = threadIdx.x & 63;
    int c = blockIdx.x * 64 + cl;
    int ks = threadIdx.x >> 6;                 // 0..3 K-slice
    const float* pr = pooled + b * D_ + ks * 512;
    const float* wp = w1 + (size_t)(ks * 512) * DC_ + c;
    float acc = 0.f;
    #pragma unroll 8
    for (int i = 0; i < 512; ++i) acc += pr[i] * wp[(size_t)i * DC_];
    red[threadIdx.x] = acc;
    __syncthreads();
    if (ks == 0) {
        float s = ((red[cl] + red[cl + 64]) + (red[cl + 128] + red[cl + 192]));
        ch[b * DC_ + c] = gelu_exact(s + b1[c]);
    }
}

__global__ void head2_k(const float* __restrict__ ch, const float* __restrict__ w2,
                        const float* __restrict__ b2, int* __restrict__ kbuf) {
    __shared__ float red[4];
    int t = threadIdx.x;
    int b = t >> 6, lane = t & 63;
    float acc = 0.f;
    #pragma unroll
    for (int i = 0; i < 8; ++i) acc += ch[b * DC_ + i * 64 + lane] * w2[i * 64 + lane];
    #pragma unroll
    for (int off = 32; off > 0; off >>= 1) acc += __shfl_down(acc, off, 64);
    if (lane == 0) {
        float z = acc + b2[0];
        float cx = 1.f / (1.f + expf(-z));
        red[b] = 0.25f + cx * 0.75f;
    }
    __syncthreads();
    if (t == 0) {
        float cap = ((red[0] + red[1]) + (red[2] + red[3])) * 0.25f;
        int kk = (int)((double)cap * (double)S_);
        if (kk < 0) kk = 0;
        if (kk > S_) kk = S_;
        kbuf[0] = kk;
    }
}

// ---------------- per-batch top-k select (radix select + compaction) ----------------
__global__ __launch_bounds__(256) void select_k(const float* __restrict__ logits,
                                                const int* __restrict__ kbuf,
                                                int* __restrict__ gidx,
                                                float* __restrict__ gwt) {
    int b = blockIdx.x;
    int t = threadIdx.x;
    int k = kbuf[0];
    __shared__ float slog[S_];
    __shared__ unsigned su[S_];
    __shared__ int hist[256];
    __shared__ unsigned sprefix;
    __shared__ int srem;
    __shared__ int sg[256], se[256];

    for (int i = t; i < S_; i += 256) {
        float f = logits[b * S_ + i];
        slog[i] = f;
        unsigned ub = __float_as_uint(f);
        su[i] = (ub & 0x80000000u) ? ~ub : (ub | 0x80000000u);
    }
    if (t == 0) { sprefix = 0u; srem = k; }
    __syncthreads();

    for (int round = 0; round < 4; ++round) {
        int shift = 24 - round * 8;
        hist[t] = 0;
        __syncthreads();
        unsigned pref = sprefix;
        unsigned pmask = (round == 0) ? 0u : ~((1u << (shift + 8)) - 1u);
        for (int i = t; i < S_; i += 256) {
            unsigned u = su[i];
            if ((u & pmask) == (pref & pmask))
                atomicAdd(&hist[(u >> shift) & 255], 1);
        }
        __syncthreads();
        if (t == 0) {
            int rem = srem, run = 0;
            for (int v = 255; v >= 0; --v) {
                int h = hist[v];
                if (run + h >= rem) {
                    srem = rem - run;
                    sprefix = pref | ((unsigned)v << shift);
                    break;
                }
                run += h;
            }
        }
        __syncthreads();
    }
    unsigned T = sprefix;
    int need_eq = srem;

    int base = t * 16;
    int local_gt = 0, local_eq = 0;
    #pragma unroll
    for (int i = 0; i < 16; ++i) {
        unsigned u = su[base + i];
        local_gt += (u > T);
        local_eq += (u == T);
    }
    sg[t] = local_gt; se[t] = local_eq;
    __syncthreads();
    for (int o = 1; o < 256; o <<= 1) {
        int vg = (t >= o) ? sg[t - o] : 0;
        int ve = (t >= o) ? se[t - o] : 0;
        __syncthreads();
        sg[t] += vg; se[t] += ve;
        __syncthreads();
    }
    int gt_excl = sg[t] - local_gt;
    int eq_excl = se[t] - local_eq;
    int total_gt = sg[255];

    int gpos = gt_excl, epos = eq_excl;
    for (int i = 0; i < 16; ++i) {
        int s = base + i;
        unsigned u = su[s];
        int pos = -1;
        if (u > T) pos = gpos++;
        else if (u == T) { if (epos < need_eq) pos = total_gt + epos; epos++; }
        if (pos >= 0) {
            gidx[b * k + pos] = b * S_ + s;
            gwt[b * k + pos] = 1.f / (1.f + expf(-slog[s]));
        }
    }
}

// ---------------- gather selected rows -> packed bf16 A ----------------
__global__ void gather_k(const float* __restrict__ hidden, const int* __restrict__ gidx,
                         const int* __restrict__ kbuf, __hip_bfloat16* __restrict__ Ag) {
    int tid = blockIdx.x * 256 + threadIdx.x;  // B_*S_*(D_/4) worst case
    int m = tid >> 9, c4 = tid & 511;
    int M = B_ * kbuf[0];
    if (m >= M) return;
    int row = gidx[m];
    float4 v = ((const float4*)(hidden + (size_t)row * D_))[c4];
    ushort4 o;
    o.x = f2bf_bits(v.x); o.y = f2bf_bits(v.y); o.z = f2bf_bits(v.z); o.w = f2bf_bits(v.w);
    ((ushort4*)Ag)[tid] = o;
}

// ---------------- fp32 -> bf16 transpose (for B^T GEMM layout) ----------------
__global__ void transpose_cvt_k(const float* __restrict__ in, __hip_bfloat16* __restrict__ out,
                                int R, int C) {
    __shared__ float tile[32][33];
    int r0 = blockIdx.y * 32, c0 = blockIdx.x * 32;
    int tx = threadIdx.x, ty = threadIdx.y;
    #pragma unroll
    for (int i = 0; i < 32; i += 8)
        tile[ty + i][tx] = in[(size_t)(r0 + ty + i) * C + (c0 + tx)];
    __syncthreads();
    #pragma unroll
    for (int i = 0; i < 32; i += 8)
        out[(size_t)(c0 + ty + i) * R + (r0 + tx)] = __float2bfloat16(tile[tx][ty + i]);
}

// Chunk-major transpose for w2: in [R=DFF_][C=D_] -> out [R/CH][C][CH].
__global__ void transpose_cvt_chunk_k(const float* __restrict__ in,
                                      __hip_bfloat16* __restrict__ out,
                                      int R, int C, int CH, int chsh) {
    __shared__ float tile[32][33];
    int r0 = blockIdx.y * 32, c0 = blockIdx.x * 32;
    int tx = threadIdx.x, ty = threadIdx.y;
    #pragma unroll
    for (int i = 0; i < 32; i += 8)
        tile[ty + i][tx] = in[(size_t)(r0 + ty + i) * C + (c0 + tx)];
    __syncthreads();
    size_t cbase = (size_t)(r0 >> chsh) * ((size_t)C * CH) + (r0 & (CH - 1)) + tx;
    #pragma unroll
    for (int i = 0; i < 32; i += 8)
        out[cbase + (size_t)(c0 + ty + i) * CH] = __float2bfloat16(tile[tx][ty + i]);
}

// =====================================================================
// 256x256 BK=64, 8-wave, 8-phase double-buffered MFMA GEMM (gload_lds).
// R7 post-mortem: FETCH=738MB == H m-panels fetched ~8x from HBM. The
// n-panel-major swizzle pinned the SMALL operand (B, 17MB) per XCD and
// scattered the 8 sharers of each 2MB H-panel across XCDs/time.
// R8 fix: m-panel-major co-scheduling -- logical id = by*nbx+bx, XCD-
// chunked, so all 8 n-blocks of one m-panel are ADJACENT on the SAME
// XCD, co-resident (320 active blocks, 2/CU), stream K in lockstep ->
// H-panel fetched once into the XCD L2 (2MB of 4MB), hit 7x. B loses
// XCD-pinning but is globally L3-resident (17MB, chunk-compact).
// =====================================================================

#define FENCE_() asm volatile("" ::: "memory")
#define BARR_()  do { FENCE_(); __builtin_amdgcn_s_barrier(); FENCE_(); } while (0)
#define VMW_()   do { asm volatile("s_waitcnt vmcnt(6)" ::: "memory"); \
                      __builtin_amdgcn_sched_barrier(0); } while (0)

template <int BN, int EPI, int SWZ>
__global__ __launch_bounds__(512, 2) void gemm8p(
    const __hip_bfloat16* __restrict__ A, int lda,
    const __hip_bfloat16* __restrict__ BT, int ldb,
    const float* __restrict__ bias,
    __hip_bfloat16* __restrict__ Hout, int ldh,
    float* __restrict__ out,
    const int* __restrict__ gidx, const float* __restrict__ gwt,
    const int* __restrict__ kbuf, int K, int first)
{
    constexpr int NQ = BN / 128;          // B frags per quadrant per wave
    constexpr int NF = 2 * NQ;            // total N frags per wave
    constexpr int BUFB = BN * 128;        // bytes per B LDS buffer
    extern __shared__ char lds[];         // A: [0,64K)  B: [64K, 64K+2*BUFB)

    const int M = B_ * kbuf[0];
    int bx, by;
    if constexpr (SWZ) {
        // active-aware m204 bijective XCD-chunk swizzle, M-PANEL-major:
        // lg = by*nbx + bx; XCD x owns a contiguous lg chunk -> the nbx
        // n-blocks of each m-panel are co-resident on one XCD and share
        // the H panel through its L2.
        const int nbx = gridDim.x;
        const int mb = (M + 255) >> 8;
        const int nact = mb * nbx;
        const int flat = blockIdx.y * nbx + blockIdx.x;
        if (flat >= nact) return;          // dead blocks exit fast
        const int q = nact >> 3, r = nact & 7;
        const int x = flat & 7, idx = flat >> 3;
        const int lg = (x < r) ? x * (q + 1) + idx
                               : r * (q + 1) + (x - r) * q + idx;
        bx = lg % nbx;
        by = lg / nbx;
    } else {
        bx = blockIdx.x; by = blockIdx.y;
    }
    const int m0 = by * 256;
    if (m0 >= M) return;
    const int n0 = bx * BN;

    const int t = threadIdx.x;
    const int lane = t & 63;
    const int wave = t >> 6;
    const int wr = wave >> 2, wc = wave & 3;   // 2 x 4 wave grid

    // staging constants: thread t covers 16B of local row rl; the source
    // column is XOR-swizzled so a linear LDS write yields swizzled content.
    const int rl = t >> 3;
    const int cbs = ((t & 7) << 4) ^ ((rl & 7) << 4);
    const int wchunk = (t >> 6) << 10;         // wave-uniform LDS chunk

    bf16x8 aR[4][2], bR[NQ][2];
    f32x4 acc[8][NF] = {};

    auto STG = [&](const __hip_bfloat16* src, int row0, int rowMax, int kcol,
                   int ld, int ldsoff) {
        int gr = row0 + rl;
        if (gr > rowMax) gr = rowMax;
        GLD16(src + (size_t)gr * ld + (kcol + (cbs >> 1)), lds + ldsoff + wchunk);
    };
    auto SA = [&](int buf, int h, int kt) {      // stage A half h (128 rows)
        int bo = buf * 32768 + h * 16384;
        STG(A, m0 + h * 128,      M - 1, kt * 64, lda, bo);
        STG(A, m0 + h * 128 + 64, M - 1, kt * 64, lda, bo + 8192);
    };
    auto SB = [&](int buf, int v, int kt) {      // stage B half v (BN/2 rows)
        int bo = 65536 + buf * BUFB + v * (BUFB / 2);
        if constexpr (BN == 256) {
            STG(BT, n0 + v * 128,      0x7fffffff, kt * 64, ldb, bo);
            STG(BT, n0 + v * 128 + 64, 0x7fffffff, kt * 64, ldb, bo + 8192);
        } else {
            STG(BT, n0 + v * 64, 0x7fffffff, kt * 64, ldb, bo);
        }
    };
    auto RA = [&](int buf, int h) {
        int bo = buf * 32768;
        #pragma unroll
        for (int q2 = 0; q2 < 4; ++q2) {
            int row = h * 128 + wr * 64 + q2 * 16 + (lane & 15);
            int ro = bo + row * 128;
            int sw = (row & 7) << 4;
            #pragma unroll
            for (int ks = 0; ks < 2; ++ks)
                aR[q2][ks] = *(const bf16x8*)(lds + ro + ((ks * 64 + ((lane >> 4) << 4)) ^ sw));
        }
    };
    auto RB = [&](int buf, int v) {
        int bo = 65536 + buf * BUFB;
        #pragma unroll
        for (int q2 = 0; q2 < NQ; ++q2) {
            int row = v * (BN / 2) + wc * (BN / 8) + q2 * 16 + (lane & 15);
            int ro = bo + row * 128;
            int sw = (row & 7) << 4;
            #pragma unroll
            for (int ks = 0; ks < 2; ++ks)
                bR[q2][ks] = *(const bf16x8*)(lds + ro + ((ks * 64 + ((lane >> 4) << 4)) ^ sw));
        }
    };
    auto MM = [&](int h, int v) {
        __builtin_amdgcn_s_setprio(1);
        #pragma unroll
        for (int mi = 0; mi < 4; ++mi)
            #pragma unroll
            for (int nj = 0; nj < NQ; ++nj)
                #pragma unroll
                for (int ks = 0; ks < 2; ++ks)
                    acc[h * 4 + mi][v * NQ + nj] = __builtin_amdgcn_mfma_f32_16x16x32_bf16(
                        aR[mi][ks], bR[nj][ks], acc[h * 4 + mi][v * NQ + nj], 0, 0, 0);
        __builtin_amdgcn_s_setprio(0);
    };

    const int nkt = K >> 6;
    const int nit = K >> 7;

    // prologue: K-tile0 fully + K-tile1 {A0,B1,A1}; tile1.B0 staged at ph1.
    SA(0, 0, 0); SA(0, 1, 0); SB(0, 0, 0); SB(0, 1, 0);
    SA(1, 0, 1); SB(1, 1, 1); SA(1, 1, 1);
    VMW_(); BARR_();

    for (int it = 0; it < nit; ++it) {
        int k1 = 2 * it + 1;
        int k2 = 2 * it + 2; if (k2 > nkt - 1) k2 = nkt - 1;
        int k3 = 2 * it + 3; if (k3 > nkt - 1) k3 = nkt - 1;
        // ph1..ph4: K-tile 2it from buf0
        RA(0, 0); RB(0, 0); SB(1, 0, k1); BARR_(); MM(0, 0); BARR_();
        RB(0, 1);           SA(0, 0, k2); BARR_(); MM(0, 1); BARR_();
        RA(0, 1);           SB(0, 1, k2); BARR_(); MM(1, 1); BARR_();
        RB(0, 0);           SA(0, 1, k2); BARR_(); MM(1, 0); VMW_(); BARR_();
        // ph5..ph8: K-tile 2it+1 from buf1
        RA(1, 0); RB(1, 0); SB(0, 0, k2); BARR_(); MM(0, 0); BARR_();
        RB(1, 1);           SA(1, 0, k3); BARR_(); MM(0, 1); BARR_();
        RA(1, 1);           SB(1, 1, k3); BARR_(); MM(1, 1); BARR_();
        RB(1, 0);           SA(1, 1, k3); BARR_(); MM(1, 0); VMW_(); BARR_();
    }
    asm volatile("s_waitcnt vmcnt(0)" ::: "memory");

    // epilogue
    const int qrow = (lane >> 4) << 2, qcol = lane & 15;
    #pragma unroll
    for (int f = 0; f < 8; ++f) {
        const int h = f >> 2, mi = f & 3;
        const int mbase = m0 + h * 128 + wr * 64 + mi * 16 + qrow;
        if constexpr (EPI == 0) {
            #pragma unroll
            for (int g = 0; g < NF; ++g) {
                const int v = g / NQ, nj = g % NQ;
                const int col = n0 + v * (BN / 2) + wc * (BN / 8) + nj * 16 + qcol;
                const float bv = bias[col];
                #pragma unroll
                for (int r = 0; r < 4; ++r) {
                    int m = mbase + r;
                    if (m < M)
                        Hout[(size_t)m * ldh + col] =
                            __float2bfloat16(gelu_exact(acc[f][g][r] + bv));
                }
            }
        } else {
            #pragma unroll
            for (int r = 0; r < 4; ++r) {
                int m = mbase + r;
                if (m < M) {
                    int grow = gidx[m];
                    float wgt = gwt[m];
                    float* orow = out + (size_t)grow * D_;
                    #pragma unroll
                    for (int g = 0; g < NF; ++g) {
                        const int v = g / NQ, nj = g % NQ;
                        const int col = n0 + v * (BN / 2) + wc * (BN / 8) + nj * 16 + qcol;
                        float vv = acc[f][g][r];
                        if (first) vv += bias[col];
                        orow[col] += wgt * vv;
                    }
                }
            }
        }
    }
}

extern "C" void kernel_launch(void* const* d_in, const int* in_sizes, int n_in,
                              void* d_out, int out_size, void* d_ws, size_t ws_size,
                              hipStream_t stream) {
    (void)in_sizes; (void)n_in;
    const float* hidden = (const float*)d_in[0];
    const float* rw  = (const float*)d_in[1];
    const float* rb  = (const float*)d_in[2];
    const float* cw1 = (const float*)d_in[3];
    const float* cb1 = (const float*)d_in[4];
    const float* cw2 = (const float*)d_in[5];
    const float* cb2 = (const float*)d_in[6];
    const float* fw1 = (const float*)d_in[7];
    const float* fb1 = (const float*)d_in[8];
    const float* fw2 = (const float*)d_in[9];
    const float* fb2 = (const float*)d_in[10];

    char* ws = (char*)d_ws;
    size_t off = 0;
    auto alloc = [&](size_t bytes) {
        size_t r = (off + 255) & ~(size_t)255;
        off = r + bytes;
        return r;
    };
    size_t o_logits = alloc((size_t)B_ * S_ * 4);
    size_t o_pp     = alloc((size_t)8 * B_ * D_ * 4);
    size_t o_pooled = alloc((size_t)B_ * D_ * 4);
    size_t o_ch     = alloc((size_t)B_ * DC_ * 4);
    size_t o_k      = alloc(256);
    size_t o_gidx   = alloc((size_t)B_ * S_ * 4);
    size_t o_gwt    = alloc((size_t)B_ * S_ * 4);
    size_t o_w1T    = alloc((size_t)D_ * DFF_ * 2);
    size_t o_w2T    = alloc((size_t)D_ * DFF_ * 2);
    size_t o_Ag     = alloc((size_t)B_ * S_ * D_ * 2);
    size_t base     = (off + 255) & ~(size_t)255;
    int CH = DFF_;
    while (CH > 256 && base + (size_t)B_ * S_ * CH * 2 > ws_size) CH >>= 1;
    size_t o_H = alloc((size_t)B_ * S_ * CH * 2);
    int chsh = 31 - __builtin_clz((unsigned)CH);

    float* logits = (float*)(ws + o_logits);
    float* pp     = (float*)(ws + o_pp);
    float* pooled = (float*)(ws + o_pooled);
    float* ch     = (float*)(ws + o_ch);
    int*   kbuf   = (int*)(ws + o_k);
    int*   gidx   = (int*)(ws + o_gidx);
    float* gwt    = (float*)(ws + o_gwt);
    __hip_bfloat16* w1T = (__hip_bfloat16*)(ws + o_w1T);
    __hip_bfloat16* w2T = (__hip_bfloat16*)(ws + o_w2T);
    __hip_bfloat16* Ag  = (__hip_bfloat16*)(ws + o_Ag);
    __hip_bfloat16* H   = (__hip_bfloat16*)(ws + o_H);
    float* out = (float*)d_out;

    // allow >64KB dynamic LDS for the 8-phase GEMMs (idempotent, ~us)
    hipError_t e;
    e = hipFuncSetAttribute((const void*)gemm8p<256, 0, 0>,
                            hipFuncAttributeMaxDynamicSharedMemorySize, 131072);
    e = hipFuncSetAttribute((const void*)gemm8p<256, 1, 1>,
                            hipFuncAttributeMaxDynamicSharedMemorySize, 131072);
    (void)e;

    pool_partial_k<<<dim3(D_ / 256, 8, B_), 256, 0, stream>>>(hidden, pp);
    pool_reduce_k<<<dim3(B_ * D_ / 256), 256, 0, stream>>>(pp, pooled);
    logits_k<<<dim3(B_ * S_ / 4), 256, 0, stream>>>(hidden, rw, rb, logits);
    head1_k<<<dim3(DC_ / 64, B_), 256, 0, stream>>>(pooled, cw1, cb1, ch);
    head2_k<<<dim3(1), 256, 0, stream>>>(ch, cw2, cb2, kbuf);
    select_k<<<dim3(B_), 256, 0, stream>>>(logits, kbuf, gidx, gwt);
    gather_k<<<dim3(B_ * S_ * (D_ / 4) / 256), 256, 0, stream>>>(hidden, gidx, kbuf, Ag);
    transpose_cvt_k<<<dim3(DFF_ / 32, D_ / 32), dim3(32, 8), 0, stream>>>(fw1, w1T, D_, DFF_);
    // w2 -> chunk-major [DFF_/CH][D_][CH]
    transpose_cvt_chunk_k<<<dim3(D_ / 32, DFF_ / 32), dim3(32, 8), 0, stream>>>(
        fw2, w2T, DFF_, D_, CH, chsh);
    hipMemcpyAsync(d_out, (const void*)hidden, (size_t)out_size * 4,
                   hipMemcpyDeviceToDevice, stream);

    int nch = DFF_ / CH;
    for (int c = 0; c < nch; ++c) {
        gemm8p<256, 0, 0><<<dim3(CH / 256, B_ * S_ / 256), 512, 131072, stream>>>(
            Ag, D_, w1T + (size_t)c * CH * D_, D_, fb1 + c * CH,
            H, CH, nullptr, nullptr, nullptr, kbuf, D_, 0);
        gemm8p<256, 1, 1><<<dim3(D_ / 256, B_ * S_ / 256), 512, 131072, stream>>>(
            H, CH, w2T + (size_t)c * D_ * CH, CH, fb2,
            nullptr, 0, out, gidx, gwt, kbuf, CH, c == 0);
    }
}